// Round 5
// baseline (357.945 us; speedup 1.0000x reference)
//
#include <hip/hip_runtime.h>
#include <cstdint>

// Problem constants (from the reference)
#define NF 23
#define ED 16
#define VTOT 205470
#define NPAIR 253            // NF*(NF-1)/2

__constant__ int OFFSETS_D[NF] = {
    0, 1000, 51000, 71000, 81000, 86000, 88000, 89000, 89500, 189500,
    197500, 201500, 203500, 204500, 205000, 205250, 205350, 205400,
    205430, 205450, 205460, 205465, 205468
};

struct PairTab { unsigned char pi[256]; unsigned char pj[256]; };
static constexpr PairTab make_pairs() {
    PairTab t{};
    int p = 0;
    for (int i = 0; i < NF; ++i)
        for (int j = i + 1; j < NF; ++j) { t.pi[p] = (unsigned char)i; t.pj[p] = (unsigned char)j; ++p; }
    for (; p < 256; ++p) { t.pi[p] = 0; t.pj[p] = 1; }
    return t;
}
__constant__ PairTab PAIRS = make_pairs();

// One 256-thread block (4 waves) per batch element.
// 256 pair-slots (253 real, 3 masked): wave w owns slots [w*64, w*64+64).
// Per iteration a wave covers 16 pairs x 4 lanes; each lane loads one float4
// of each operand vector. 4 iterations fully unrolled -> 8 independent
// 16B gathers per lane, issued back-to-back (invalid slots load the
// already-hot pair-0 lines and are masked in the FMA) -> one memory wait
// per wave instead of 4+, and 4x the resident waves of the previous version.
__global__ __launch_bounds__(256) void ffm_kernel(
    const int* __restrict__ x,      // [B, NF] per-field indices
    const float* __restrict__ E,    // [NF, VTOT, ED]
    const float* __restrict__ W,    // [VTOT, 1]
    const float* __restrict__ bias, // [1]
    float* __restrict__ out)        // [B]
{
    __shared__ int   s_idx[NF];
    __shared__ float s_part[4];

    const int tid  = threadIdx.x;
    const int lane = tid & 63;
    const int wid  = tid >> 6;
    const int b    = blockIdx.x;

    float acc = 0.0f;

    // Stage global indices; fold linear term into wave 0's accumulator.
    if (tid < NF) {
        const int ix = x[b * NF + tid] + OFFSETS_D[tid];
        s_idx[tid] = ix;
        acc = W[ix];
    }
    __syncthreads();

    const int grp = lane >> 2;   // pair within iteration (0..15)
    const int dq  = lane & 3;    // which float4 of the 16-d vector

    // Phase 1: issue all 8 gathers unconditionally.
    float4 av[4], cv[4];
    bool   vld[4];
    #pragma unroll
    for (int it = 0; it < 4; ++it) {
        const int p  = wid * 64 + it * 16 + grp;
        vld[it] = (p < NPAIR);
        const int ps = vld[it] ? p : 0;
        const int i  = PAIRS.pi[ps];
        const int j  = PAIRS.pj[ps];
        // 302 MB table -> 32-bit element offsets suffice.
        const unsigned off_a = (unsigned)(i * VTOT + s_idx[j]) * ED + dq * 4;
        const unsigned off_c = (unsigned)(j * VTOT + s_idx[i]) * ED + dq * 4;
        av[it] = *reinterpret_cast<const float4*>(E + off_a);
        cv[it] = *reinterpret_cast<const float4*>(E + off_c);
    }

    // Phase 2: masked dot-product accumulate.
    #pragma unroll
    for (int it = 0; it < 4; ++it) {
        const float m = vld[it] ? 1.0f : 0.0f;
        acc += m * (av[it].x * cv[it].x + av[it].y * cv[it].y +
                    av[it].z * cv[it].z + av[it].w * cv[it].w);
    }

    // Wave reduction, then cross-wave combine in LDS.
    #pragma unroll
    for (int off = 32; off; off >>= 1) acc += __shfl_xor(acc, off, 64);
    if (lane == 0) s_part[wid] = acc;
    __syncthreads();

    if (tid == 0) {
        const float z = s_part[0] + s_part[1] + s_part[2] + s_part[3] + bias[0];
        out[b] = 1.0f / (1.0f + __expf(-z));
    }
}

extern "C" void kernel_launch(void* const* d_in, const int* in_sizes, int n_in,
                              void* d_out, int out_size, void* d_ws, size_t ws_size,
                              hipStream_t stream) {
    const int*   x    = (const int*)d_in[0];    // [B, NF] int32
    const float* E    = (const float*)d_in[1];  // [NF, VTOT, ED] f32
    const float* W    = (const float*)d_in[2];  // [VTOT, 1] f32
    const float* bias = (const float*)d_in[3];  // [1] f32
    float* out = (float*)d_out;

    const int B = in_sizes[0] / NF;             // 4096
    ffm_kernel<<<B, 256, 0, stream>>>(x, E, W, bias, out);
}